// Round 8
// baseline (279.113 us; speedup 1.0000x reference)
//
#include <hip/hip_runtime.h>
#include <hip/hip_bf16.h>

#define N_NODES 131072
#define B_SEG   2048
#define F_DIM   200
#define K_DIM   608      // 400 (q_star) + 200 (h) + 8 zero pad = 19*32
#define NEG_INF (-3.4e38f)

typedef __attribute__((ext_vector_type(8))) short bf16x8;
typedef __attribute__((ext_vector_type(4))) float f32x4;

__device__ __forceinline__ float b2f(unsigned short u) {
  union { unsigned int i; float f; } v; v.i = ((unsigned int)u) << 16; return v.f;
}
__device__ __forceinline__ unsigned short f2bu(float f) {
  __hip_bfloat16 h = __float2bfloat16(f);
  return *reinterpret_cast<unsigned short*>(&h);
}
__device__ __forceinline__ float sigmoidf_(float x) { return 1.f / (1.f + __expf(-x)); }
__device__ __forceinline__ int lower_bound(const int* __restrict__ a, int n, int v) {
  int lo = 0, hi = n;
  while (lo < hi) { int mid = (lo + hi) >> 1; if (a[mid] < v) lo = mid + 1; else hi = mid; }
  return lo;
}

// ---- merged setup+init: blocks 0..2047 init (own binary search);
//      2048..4023 pack Wc; 4024..4535 soff; 4536..4539 bsum + soff tail ----
__global__ __launch_bounds__(256) void init_setup_kernel(
    const float* __restrict__ xf, const int* __restrict__ batch,
    const float* __restrict__ cosc, const float* __restrict__ qs0,
    const float* __restrict__ Wih, const float* __restrict__ Whh,
    const float* __restrict__ bih, const float* __restrict__ bhh,
    unsigned short* __restrict__ xb, unsigned short* __restrict__ A,
    unsigned short* __restrict__ Wc, float* __restrict__ bsum,
    int* __restrict__ seg_off) {
  int bid = blockIdx.x, tid = threadIdx.x;
  if (bid >= 2048) {
    if (bid < 4024) {                      // Wc pack: 832*608 = 1976*256
      int idx = (bid - 2048) * 256 + tid;
      int row = idx / K_DIM, k = idx - row * K_DIM;
      float v = 0.f;
      if (row < 800) {
        if (k < 400)      v = Wih[row * 400 + k];
        else if (k < 600) v = Whh[row * 200 + (k - 400)];
      }
      Wc[idx] = f2bu(v);
    } else if (bid < 4536) {               // seg offsets: 512*256 = 131072
      int i = (bid - 4024) * 256 + tid;
      int v  = batch[i];
      int pv = (i == 0) ? -1 : batch[i - 1];
      for (int b = pv + 1; b <= v; b++) seg_off[b] = i;
    } else {                               // bsum + trailing seg_off
      int idx = (bid - 4536) * 256 + tid;
      if (idx < 800) bsum[idx] = bih[idx] + bhh[idx];
      else if (idx == 800) {
        int last = batch[N_NODES - 1];
        for (int b = last + 1; b <= B_SEG; b++) seg_off[b] = N_NODES;
      }
    }
    return;
  }
  // ---- init for segment b = bid (binary search; soff not yet valid) ----
  __shared__ float rpart[5][F_DIM];
  int b = bid;
  int start = lower_bound(batch, N_NODES, b);
  int end   = lower_bound(batch, N_NODES, b + 1);
  int n = end - start;
  unsigned short* Arow = A + (size_t)b * K_DIM;
  int rgrp = tid / 50, col4 = tid - rgrp * 50;   // rgrp 0..4 active, col4 0..49
  float a0 = 0.f, a1 = 0.f, a2 = 0.f, a3 = 0.f;
  if (rgrp < 5) {
    int r = rgrp;
    float4 vc; float cc = 0.f;
    if (r < n) {
      vc = *(const float4*)(xf + (size_t)(start + r) * F_DIM + 4 * col4);
      cc = cosc[start + r];
    }
    while (r < n) {
      int rn = r + 5;
      float4 vn; float cn2 = 0.f;
      if (rn < n) {                        // prefetch next row before processing
        vn = *(const float4*)(xf + (size_t)(start + rn) * F_DIM + 4 * col4);
        cn2 = cosc[start + rn];
      }
      ushort4 o; o.x = f2bu(vc.x); o.y = f2bu(vc.y); o.z = f2bu(vc.z); o.w = f2bu(vc.w);
      *(ushort4*)(xb + (size_t)(start + r) * F_DIM + 4 * col4) = o;
      a0 += cc * b2f(o.x); a1 += cc * b2f(o.y);
      a2 += cc * b2f(o.z); a3 += cc * b2f(o.w);
      vc = vn; cc = cn2; r = rn;
    }
    rpart[rgrp][4 * col4]     = a0;
    rpart[rgrp][4 * col4 + 1] = a1;
    rpart[rgrp][4 * col4 + 2] = a2;
    rpart[rgrp][4 * col4 + 3] = a3;
  }
  if (tid < 100) {                         // qs0 row: 400 f32 -> 400 bf16
    float4 v = *(const float4*)(qs0 + (size_t)b * 400 + 4 * tid);
    ushort4 o; o.x = f2bu(v.x); o.y = f2bu(v.y); o.z = f2bu(v.z); o.w = f2bu(v.w);
    *(ushort4*)(Arow + 4 * tid) = o;
  }
  if (tid < 8) Arow[600 + tid] = 0;
  __syncthreads();
  if (tid < F_DIM) {
    float acc = rpart[0][tid] + rpart[1][tid] + rpart[2][tid] + rpart[3][tid]
              + rpart[4][tid];
    Arow[400 + tid] = f2bu(acc);
  }
}

// ---- gates GEMM, barrier-free, BM=32/BN=64: 832 blocks ----
__global__ __launch_bounds__(256) void gemm_gates(
    const unsigned short* __restrict__ A, const unsigned short* __restrict__ W,
    float* __restrict__ gates) {
  int tid = threadIdx.x;
  int bm = blockIdx.x * 32, bn = blockIdx.y * 64;
  int wave = tid >> 6, lane = tid & 63;
  int quad = lane >> 4, col = lane & 15;
  int strip = wave >> 1;                  // 0..1 : 16-row strip
  int tp = (wave & 1) * 2;                // 0 or 2 : N-tile pair
  f32x4 acc[2];
  acc[0] = (f32x4){0.f, 0.f, 0.f, 0.f};
  acc[1] = (f32x4){0.f, 0.f, 0.f, 0.f};
  const unsigned short* Ap = A + (size_t)(bm + strip * 16 + col) * K_DIM + quad * 8;
  const unsigned short* Wp = W + (size_t)(bn + col) * K_DIM + quad * 8;
#pragma unroll
  for (int k0 = 0; k0 < K_DIM; k0 += 32) {
    bf16x8 af = *(const bf16x8*)(Ap + k0);
#pragma unroll
    for (int t = 0; t < 2; t++) {
      bf16x8 bfr = *(const bf16x8*)(Wp + (size_t)(tp + t) * 16 * K_DIM + k0);
      acc[t] = __builtin_amdgcn_mfma_f32_16x16x32_bf16(af, bfr, acc[t], 0, 0, 0);
    }
  }
#pragma unroll
  for (int t = 0; t < 2; t++) {
    int gn = bn + (tp + t) * 16 + col;
    if (gn < 800) {
#pragma unroll
      for (int r = 0; r < 4; r++) {
        int gm = bm + strip * 16 + quad * 4 + r;
        gates[(size_t)gm * 800 + gn] = acc[t][r];
      }
    }
  }
}

// ---- fused LSTM cell + online-softmax attention, half-wave per row ----
__global__ __launch_bounds__(256) void attn_fused(
    const unsigned short* __restrict__ xb, const int* __restrict__ seg_off,
    const float* __restrict__ gates, const float* __restrict__ bsum,
    float* __restrict__ cvec, unsigned short* __restrict__ A,
    float* __restrict__ out, int step) {
  __shared__ float q_s[F_DIM];
  __shared__ float rpart[8][F_DIM];
  __shared__ float redm[8], redl[8];
  int b = blockIdx.x, tid = threadIdx.x;
  int start = seg_off[b], end = seg_off[b + 1];
  int n = end - start;
  unsigned short* Arow = A + (size_t)b * K_DIM;
  // LSTM cell for this segment's 200 features
  if (tid < F_DIM) {
    int f = tid;
    const float* g = gates + (size_t)b * 800;
    float gi = g[f]       + bsum[f];
    float gf = g[200 + f] + bsum[200 + f];
    float gg = g[400 + f] + bsum[400 + f];
    float go = g[600 + f] + bsum[600 + f];
    float cp = (step > 0) ? cvec[(size_t)b * F_DIM + f] : 0.f;
    float cn = sigmoidf_(gf) * cp + sigmoidf_(gi) * tanhf(gg);
    float hn = sigmoidf_(go) * tanhf(cn);
    cvec[(size_t)b * F_DIM + f] = cn;
    q_s[f] = hn;
    if (step < 2) {
      unsigned short hb = f2bu(hn);
      Arow[f] = hb;                       // q part of next q_star
      Arow[400 + f] = hb;                 // hidden for next cell
    }
  }
  __syncthreads();
  int wave = tid >> 6, lane = tid & 63;
  int half = lane >> 5, hl = lane & 31;   // 32-lane half-wave
  int hw = wave * 2 + half;               // 0..7 : row owner
  bool act = (hl < 25);                   // 25 lanes x 8 elems = 200 features
  float q0=0,q1=0,q2=0,q3=0,q4=0,q5=0,q6=0,q7=0;
  if (act) {
    q0 = q_s[8*hl];   q1 = q_s[8*hl+1]; q2 = q_s[8*hl+2]; q3 = q_s[8*hl+3];
    q4 = q_s[8*hl+4]; q5 = q_s[8*hl+5]; q6 = q_s[8*hl+6]; q7 = q_s[8*hl+7];
  }
  const unsigned short* xp = xb + (size_t)start * F_DIM + 8 * hl;
  // online softmax: single pass, prefetch next row while processing current
  float m = NEG_INF, l = 0.f;
  float a0=0,a1=0,a2=0,a3=0,a4=0,a5=0,a6=0,a7=0;
  int r = hw;
  uint4 vc = (uint4){0,0,0,0};
  if (act && r < n) vc = *(const uint4*)(xp + (size_t)r * F_DIM);
  while (r < n) {
    int rn = r + 8;
    uint4 vn = (uint4){0,0,0,0};
    if (act && rn < n) vn = *(const uint4*)(xp + (size_t)rn * F_DIM);
    float x0=0,x1=0,x2=0,x3=0,x4=0,x5=0,x6=0,x7=0;
    float p = 0.f;
    if (act) {
      x0 = b2f((unsigned short)(vc.x & 0xffff)); x1 = b2f((unsigned short)(vc.x >> 16));
      x2 = b2f((unsigned short)(vc.y & 0xffff)); x3 = b2f((unsigned short)(vc.y >> 16));
      x4 = b2f((unsigned short)(vc.z & 0xffff)); x5 = b2f((unsigned short)(vc.z >> 16));
      x6 = b2f((unsigned short)(vc.w & 0xffff)); x7 = b2f((unsigned short)(vc.w >> 16));
      p = q0*x0 + q1*x1 + q2*x2 + q3*x3 + q4*x4 + q5*x5 + q6*x6 + q7*x7;
    }
#pragma unroll
    for (int off = 16; off; off >>= 1) p += __shfl_xor(p, off, 32);
    float e = p;
    float mn = fmaxf(m, e);
    float fac = __expf(m - mn);           // first iter: exp(-inf)=0
    float w  = __expf(e - mn);
    l  = l * fac + w;
    a0 = a0*fac + w*x0; a1 = a1*fac + w*x1; a2 = a2*fac + w*x2; a3 = a3*fac + w*x3;
    a4 = a4*fac + w*x4; a5 = a5*fac + w*x5; a6 = a6*fac + w*x6; a7 = a7*fac + w*x7;
    m = mn;
    vc = vn; r = rn;
  }
  // cross-half-wave combine: 8 (m,l,a) triples
  if (hl == 0) redm[hw] = m;
  __syncthreads();
  float M = fmaxf(fmaxf(fmaxf(redm[0], redm[1]), fmaxf(redm[2], redm[3])),
                  fmaxf(fmaxf(redm[4], redm[5]), fmaxf(redm[6], redm[7])));
  float facw = (m > NEG_INF) ? __expf(m - M) : 0.f;
  if (hl == 0) redl[hw] = l * facw;
  if (act) {
    float* rp = &rpart[hw][8 * hl];
    rp[0] = a0*facw; rp[1] = a1*facw; rp[2] = a2*facw; rp[3] = a3*facw;
    rp[4] = a4*facw; rp[5] = a5*facw; rp[6] = a6*facw; rp[7] = a7*facw;
  }
  __syncthreads();
  float L = redl[0]+redl[1]+redl[2]+redl[3]+redl[4]+redl[5]+redl[6]+redl[7];
  float inv = (L > 0.f) ? 1.f / L : 0.f;
  if (tid < F_DIM) {
    float rv = (rpart[0][tid]+rpart[1][tid]+rpart[2][tid]+rpart[3][tid]
              + rpart[4][tid]+rpart[5][tid]+rpart[6][tid]+rpart[7][tid]) * inv;
    if (step < 2) {
      Arow[200 + tid] = f2bu(rv);
    } else {
      out[(size_t)b * 400 + tid]       = q_s[tid];
      out[(size_t)b * 400 + 200 + tid] = rv;
    }
  }
}

extern "C" void kernel_launch(void* const* d_in, const int* in_sizes, int n_in,
                              void* d_out, int out_size, void* d_ws, size_t ws_size,
                              hipStream_t stream) {
  const float* x    = (const float*)d_in[0];
  const int*   batch= (const int*)d_in[1];
  const float* cosc = (const float*)d_in[2];
  const float* qs0  = (const float*)d_in[3];
  const float* Wih  = (const float*)d_in[4];
  const float* Whh  = (const float*)d_in[5];
  const float* bih  = (const float*)d_in[6];
  const float* bhh  = (const float*)d_in[7];
  char* ws = (char*)d_ws;
  // ws layout (bytes, all 16B aligned), total ~64.2 MB:
  unsigned short* xb   = (unsigned short*)(ws);               // 131072*200*2 = 52,428,800
  unsigned short* A    = (unsigned short*)(ws + 52428800);    // 2048*608*2   =  2,490,368
  unsigned short* Wc   = (unsigned short*)(ws + 54919168);    // 832*608*2    =  1,011,712
  float*          gates= (float*)(ws + 55930880);             // 2048*800*4   =  6,553,600
  float*          cvec = (float*)(ws + 62484480);             // 2048*200*4   =  1,638,400
  float*          bsum = (float*)(ws + 64122880);             // 800*4        =      3,200
  int*            soff = (int*)(ws + 64126080);               // 2052*4       =      8,208
  float*          outp = (float*)d_out;

  init_setup_kernel<<<4540, 256, 0, stream>>>(x, batch, cosc, qs0, Wih, Whh,
                                              bih, bhh, xb, A, Wc, bsum, soff);
  for (int s = 0; s < 3; s++) {
    gemm_gates<<<dim3(64, 13), 256, 0, stream>>>(A, Wc, gates);
    attn_fused<<<B_SEG, 256, 0, stream>>>(xb, soff, gates, bsum, cvec, A, outp, s);
  }
}

// Round 9
// 277.308 us; speedup vs baseline: 1.0065x; 1.0065x over previous
//
#include <hip/hip_runtime.h>
#include <hip/hip_bf16.h>

#define N_NODES 131072
#define B_SEG   2048
#define F_DIM   200
#define K_DIM   608      // 400 (q_star) + 200 (h) + 8 zero pad = 19*32
#define NEG_INF (-3.4e38f)
#define CONV_B  3200     // convert blocks: 3200*256*8 float4 == N*F/4 exactly
#define CONV_T  (CONV_B * 256)

typedef __attribute__((ext_vector_type(8))) short bf16x8;
typedef __attribute__((ext_vector_type(4))) float f32x4;

__device__ __forceinline__ float b2f(unsigned short u) {
  union { unsigned int i; float f; } v; v.i = ((unsigned int)u) << 16; return v.f;
}
__device__ __forceinline__ unsigned short f2bu(float f) {
  __hip_bfloat16 h = __float2bfloat16(f);
  return *reinterpret_cast<unsigned short*>(&h);
}
__device__ __forceinline__ float sigmoidf_(float x) { return 1.f / (1.f + __expf(-x)); }

// ---- convert (grid-stride, 8-deep MLP) + Wc pack + soff + bsum ----
__global__ __launch_bounds__(256) void convert_setup_kernel(
    const float* __restrict__ xf, const int* __restrict__ batch,
    const float* __restrict__ Wih, const float* __restrict__ Whh,
    const float* __restrict__ bih, const float* __restrict__ bhh,
    unsigned short* __restrict__ xb, unsigned short* __restrict__ Wc,
    float* __restrict__ bsum, int* __restrict__ seg_off) {
  int bid = blockIdx.x, tid = threadIdx.x;
  if (bid < CONV_B) {                      // x f32 -> bf16, 8 float4 per thread
    int t = bid * 256 + tid;
    const float4* src = (const float4*)xf;
    ushort4* dst = (ushort4*)xb;
    float4 v[8];
#pragma unroll
    for (int j = 0; j < 8; j++) v[j] = src[t + j * CONV_T];
#pragma unroll
    for (int j = 0; j < 8; j++) {
      ushort4 o; o.x = f2bu(v[j].x); o.y = f2bu(v[j].y);
      o.z = f2bu(v[j].z); o.w = f2bu(v[j].w);
      dst[t + j * CONV_T] = o;
    }
  } else if (bid < CONV_B + 1976) {        // Wc pack: 832*608 = 1976*256
    int idx = (bid - CONV_B) * 256 + tid;
    int row = idx / K_DIM, k = idx - row * K_DIM;
    float v = 0.f;
    if (row < 800) {
      if (k < 400)      v = Wih[row * 400 + k];
      else if (k < 600) v = Whh[row * 200 + (k - 400)];
    }
    Wc[idx] = f2bu(v);
  } else if (bid < CONV_B + 1976 + 512) {  // seg offsets: 512*256 = 131072
    int i = (bid - CONV_B - 1976) * 256 + tid;
    int v  = batch[i];
    int pv = (i == 0) ? -1 : batch[i - 1];
    for (int b = pv + 1; b <= v; b++) seg_off[b] = i;
  } else {                                 // bsum + trailing seg_off
    int idx = (bid - CONV_B - 2488) * 256 + tid;
    if (idx < 800) bsum[idx] = bih[idx] + bhh[idx];
    else if (idx == 800) {
      int last = batch[N_NODES - 1];
      for (int b = last + 1; b <= B_SEG; b++) seg_off[b] = N_NODES;
    }
  }
}

// ---- h0: per-segment seg_sum(cos*xb), half-wave per row; + A row pack ----
__global__ __launch_bounds__(256) void h0_kernel(
    const unsigned short* __restrict__ xb, const int* __restrict__ seg_off,
    const float* __restrict__ cosc, const float* __restrict__ qs0,
    unsigned short* __restrict__ A) {
  __shared__ float rpart[8][F_DIM];
  int b = blockIdx.x, tid = threadIdx.x;
  int start = seg_off[b], end = seg_off[b + 1];
  int n = end - start;
  unsigned short* Arow = A + (size_t)b * K_DIM;
  if (tid < 100) {                         // qs0 row: 400 f32 -> 400 bf16
    float4 v = *(const float4*)(qs0 + (size_t)b * 400 + 4 * tid);
    ushort4 o; o.x = f2bu(v.x); o.y = f2bu(v.y); o.z = f2bu(v.z); o.w = f2bu(v.w);
    *(ushort4*)(Arow + 4 * tid) = o;
  }
  if (tid < 8) Arow[600 + tid] = 0;
  int wave = tid >> 6, lane = tid & 63;
  int half = lane >> 5, hl = lane & 31;
  int hw = wave * 2 + half;                // 0..7 row-stream owner
  bool act = (hl < 25);
  const unsigned short* xp = xb + (size_t)start * F_DIM + 8 * hl;
  float a0=0,a1=0,a2=0,a3=0,a4=0,a5=0,a6=0,a7=0;
  int r = hw;
  uint4 vc = (uint4){0,0,0,0}; float cc = 0.f;
  if (r < n) { if (act) vc = *(const uint4*)(xp + (size_t)r * F_DIM); cc = cosc[start + r]; }
  while (r < n) {
    int rn = r + 8;
    uint4 vn = (uint4){0,0,0,0}; float cn2 = 0.f;
    if (rn < n) { if (act) vn = *(const uint4*)(xp + (size_t)rn * F_DIM); cn2 = cosc[start + rn]; }
    if (act) {
      a0 += cc * b2f((unsigned short)(vc.x & 0xffff));
      a1 += cc * b2f((unsigned short)(vc.x >> 16));
      a2 += cc * b2f((unsigned short)(vc.y & 0xffff));
      a3 += cc * b2f((unsigned short)(vc.y >> 16));
      a4 += cc * b2f((unsigned short)(vc.z & 0xffff));
      a5 += cc * b2f((unsigned short)(vc.z >> 16));
      a6 += cc * b2f((unsigned short)(vc.w & 0xffff));
      a7 += cc * b2f((unsigned short)(vc.w >> 16));
    }
    vc = vn; cc = cn2; r = rn;
  }
  if (act) {
    float* rp = &rpart[hw][8 * hl];
    rp[0]=a0; rp[1]=a1; rp[2]=a2; rp[3]=a3; rp[4]=a4; rp[5]=a5; rp[6]=a6; rp[7]=a7;
  }
  __syncthreads();
  if (tid < F_DIM) {
    float acc = rpart[0][tid]+rpart[1][tid]+rpart[2][tid]+rpart[3][tid]
              + rpart[4][tid]+rpart[5][tid]+rpart[6][tid]+rpart[7][tid];
    Arow[400 + tid] = f2bu(acc);
  }
}

// ---- gates GEMM, barrier-free, BM=32/BN=64: 832 blocks ----
__global__ __launch_bounds__(256) void gemm_gates(
    const unsigned short* __restrict__ A, const unsigned short* __restrict__ W,
    float* __restrict__ gates) {
  int tid = threadIdx.x;
  int bm = blockIdx.x * 32, bn = blockIdx.y * 64;
  int wave = tid >> 6, lane = tid & 63;
  int quad = lane >> 4, col = lane & 15;
  int strip = wave >> 1;                  // 0..1 : 16-row strip
  int tp = (wave & 1) * 2;                // 0 or 2 : N-tile pair
  f32x4 acc[2];
  acc[0] = (f32x4){0.f, 0.f, 0.f, 0.f};
  acc[1] = (f32x4){0.f, 0.f, 0.f, 0.f};
  const unsigned short* Ap = A + (size_t)(bm + strip * 16 + col) * K_DIM + quad * 8;
  const unsigned short* Wp = W + (size_t)(bn + col) * K_DIM + quad * 8;
#pragma unroll
  for (int k0 = 0; k0 < K_DIM; k0 += 32) {
    bf16x8 af = *(const bf16x8*)(Ap + k0);
#pragma unroll
    for (int t = 0; t < 2; t++) {
      bf16x8 bfr = *(const bf16x8*)(Wp + (size_t)(tp + t) * 16 * K_DIM + k0);
      acc[t] = __builtin_amdgcn_mfma_f32_16x16x32_bf16(af, bfr, acc[t], 0, 0, 0);
    }
  }
#pragma unroll
  for (int t = 0; t < 2; t++) {
    int gn = bn + (tp + t) * 16 + col;
    if (gn < 800) {
#pragma unroll
      for (int r = 0; r < 4; r++) {
        int gm = bm + strip * 16 + quad * 4 + r;
        gates[(size_t)gm * 800 + gn] = acc[t][r];
      }
    }
  }
}

// ---- fused LSTM cell + online-softmax attention, half-wave per row ----
__global__ __launch_bounds__(256) void attn_fused(
    const unsigned short* __restrict__ xb, const int* __restrict__ seg_off,
    const float* __restrict__ gates, const float* __restrict__ bsum,
    float* __restrict__ cvec, unsigned short* __restrict__ A,
    float* __restrict__ out, int step) {
  __shared__ float q_s[F_DIM];
  __shared__ float rpart[8][F_DIM];
  __shared__ float redm[8], redl[8];
  int b = blockIdx.x, tid = threadIdx.x;
  int start = seg_off[b], end = seg_off[b + 1];
  int n = end - start;
  unsigned short* Arow = A + (size_t)b * K_DIM;
  // LSTM cell for this segment's 200 features
  if (tid < F_DIM) {
    int f = tid;
    const float* g = gates + (size_t)b * 800;
    float gi = g[f]       + bsum[f];
    float gf = g[200 + f] + bsum[200 + f];
    float gg = g[400 + f] + bsum[400 + f];
    float go = g[600 + f] + bsum[600 + f];
    float cp = (step > 0) ? cvec[(size_t)b * F_DIM + f] : 0.f;
    float cn = sigmoidf_(gf) * cp + sigmoidf_(gi) * tanhf(gg);
    float hn = sigmoidf_(go) * tanhf(cn);
    cvec[(size_t)b * F_DIM + f] = cn;
    q_s[f] = hn;
    if (step < 2) {
      unsigned short hb = f2bu(hn);
      Arow[f] = hb;                       // q part of next q_star
      Arow[400 + f] = hb;                 // hidden for next cell
    }
  }
  __syncthreads();
  int wave = tid >> 6, lane = tid & 63;
  int half = lane >> 5, hl = lane & 31;   // 32-lane half-wave
  int hw = wave * 2 + half;               // 0..7 : row owner
  bool act = (hl < 25);                   // 25 lanes x 8 elems = 200 features
  float q0=0,q1=0,q2=0,q3=0,q4=0,q5=0,q6=0,q7=0;
  if (act) {
    q0 = q_s[8*hl];   q1 = q_s[8*hl+1]; q2 = q_s[8*hl+2]; q3 = q_s[8*hl+3];
    q4 = q_s[8*hl+4]; q5 = q_s[8*hl+5]; q6 = q_s[8*hl+6]; q7 = q_s[8*hl+7];
  }
  const unsigned short* xp = xb + (size_t)start * F_DIM + 8 * hl;
  // online softmax: single pass, prefetch next row while processing current
  float m = NEG_INF, l = 0.f;
  float a0=0,a1=0,a2=0,a3=0,a4=0,a5=0,a6=0,a7=0;
  int r = hw;
  uint4 vc = (uint4){0,0,0,0};
  if (act && r < n) vc = *(const uint4*)(xp + (size_t)r * F_DIM);
  while (r < n) {
    int rn = r + 8;
    uint4 vn = (uint4){0,0,0,0};
    if (act && rn < n) vn = *(const uint4*)(xp + (size_t)rn * F_DIM);
    float x0=0,x1=0,x2=0,x3=0,x4=0,x5=0,x6=0,x7=0;
    float p = 0.f;
    if (act) {
      x0 = b2f((unsigned short)(vc.x & 0xffff)); x1 = b2f((unsigned short)(vc.x >> 16));
      x2 = b2f((unsigned short)(vc.y & 0xffff)); x3 = b2f((unsigned short)(vc.y >> 16));
      x4 = b2f((unsigned short)(vc.z & 0xffff)); x5 = b2f((unsigned short)(vc.z >> 16));
      x6 = b2f((unsigned short)(vc.w & 0xffff)); x7 = b2f((unsigned short)(vc.w >> 16));
      p = q0*x0 + q1*x1 + q2*x2 + q3*x3 + q4*x4 + q5*x5 + q6*x6 + q7*x7;
    }
#pragma unroll
    for (int off = 16; off; off >>= 1) p += __shfl_xor(p, off, 32);
    float e = p;
    float mn = fmaxf(m, e);
    float fac = __expf(m - mn);           // first iter: exp(-inf)=0
    float w  = __expf(e - mn);
    l  = l * fac + w;
    a0 = a0*fac + w*x0; a1 = a1*fac + w*x1; a2 = a2*fac + w*x2; a3 = a3*fac + w*x3;
    a4 = a4*fac + w*x4; a5 = a5*fac + w*x5; a6 = a6*fac + w*x6; a7 = a7*fac + w*x7;
    m = mn;
    vc = vn; r = rn;
  }
  // cross-half-wave combine: 8 (m,l,a) triples
  if (hl == 0) redm[hw] = m;
  __syncthreads();
  float M = fmaxf(fmaxf(fmaxf(redm[0], redm[1]), fmaxf(redm[2], redm[3])),
                  fmaxf(fmaxf(redm[4], redm[5]), fmaxf(redm[6], redm[7])));
  float facw = (m > NEG_INF) ? __expf(m - M) : 0.f;
  if (hl == 0) redl[hw] = l * facw;
  if (act) {
    float* rp = &rpart[hw][8 * hl];
    rp[0] = a0*facw; rp[1] = a1*facw; rp[2] = a2*facw; rp[3] = a3*facw;
    rp[4] = a4*facw; rp[5] = a5*facw; rp[6] = a6*facw; rp[7] = a7*facw;
  }
  __syncthreads();
  float L = redl[0]+redl[1]+redl[2]+redl[3]+redl[4]+redl[5]+redl[6]+redl[7];
  float inv = (L > 0.f) ? 1.f / L : 0.f;
  if (tid < F_DIM) {
    float rv = (rpart[0][tid]+rpart[1][tid]+rpart[2][tid]+rpart[3][tid]
              + rpart[4][tid]+rpart[5][tid]+rpart[6][tid]+rpart[7][tid]) * inv;
    if (step < 2) {
      Arow[200 + tid] = f2bu(rv);
    } else {
      out[(size_t)b * 400 + tid]       = q_s[tid];
      out[(size_t)b * 400 + 200 + tid] = rv;
    }
  }
}

extern "C" void kernel_launch(void* const* d_in, const int* in_sizes, int n_in,
                              void* d_out, int out_size, void* d_ws, size_t ws_size,
                              hipStream_t stream) {
  const float* x    = (const float*)d_in[0];
  const int*   batch= (const int*)d_in[1];
  const float* cosc = (const float*)d_in[2];
  const float* qs0  = (const float*)d_in[3];
  const float* Wih  = (const float*)d_in[4];
  const float* Whh  = (const float*)d_in[5];
  const float* bih  = (const float*)d_in[6];
  const float* bhh  = (const float*)d_in[7];
  char* ws = (char*)d_ws;
  // ws layout (bytes, all 16B aligned), total ~64.2 MB:
  unsigned short* xb   = (unsigned short*)(ws);               // 131072*200*2 = 52,428,800
  unsigned short* A    = (unsigned short*)(ws + 52428800);    // 2048*608*2   =  2,490,368
  unsigned short* Wc   = (unsigned short*)(ws + 54919168);    // 832*608*2    =  1,011,712
  float*          gates= (float*)(ws + 55930880);             // 2048*800*4   =  6,553,600
  float*          cvec = (float*)(ws + 62484480);             // 2048*200*4   =  1,638,400
  float*          bsum = (float*)(ws + 64122880);             // 800*4        =      3,200
  int*            soff = (int*)(ws + 64126080);               // 2052*4       =      8,208
  float*          outp = (float*)d_out;

  convert_setup_kernel<<<CONV_B + 1976 + 512 + 4, 256, 0, stream>>>(
      x, batch, Wih, Whh, bih, bhh, xb, Wc, bsum, soff);
  h0_kernel<<<B_SEG, 256, 0, stream>>>(xb, soff, cosc, qs0, A);
  for (int s = 0; s < 3; s++) {
    gemm_gates<<<dim3(64, 13), 256, 0, stream>>>(A, Wc, gates);
    attn_fused<<<B_SEG, 256, 0, stream>>>(xb, soff, gates, bsum, cvec, A, outp, s);
  }
}